// Round 7
// baseline (605.867 us; speedup 1.0000x reference)
//
#include <hip/hip_runtime.h>
#include <hip/hip_bf16.h>

typedef short short8 __attribute__((ext_vector_type(8)));
typedef float f32x4 __attribute__((ext_vector_type(4)));
typedef float f32x2 __attribute__((ext_vector_type(2)));

#if __has_builtin(__builtin_elementwise_fma)
#define FMA2(a, b, c) __builtin_elementwise_fma((a), (b), (c))
#else
#define FMA2(a, b, c) ((a) * (b) + (c))
#endif

namespace {
constexpr int Bn = 2, Cn = 64, Dn = 16, Hn = 64, Wn = 64;
constexpr int Gn = 2, Kn = 27, GCn = 32;
constexpr int DHW = Dn * Hn * Wn;                 // 65536
constexpr int OCn = 216;                          // 162 off + 54 mask
constexpr int PD = 18, PH = 66, PW = 66;
constexpr float EPS = 1e-5f;

constexpr size_t XPADH_OFF = 0;
constexpr size_t XPADH_B   = (size_t)Bn * PD * PH * PW * Cn * 2;   // 20,072,448
constexpr size_t WFRAG_OFF = XPADH_OFF + XPADH_B;
constexpr size_t WFRAG_B   = (size_t)54 * 16 * 64 * 16;            // 884,736
constexpr size_t WV_OFF    = WFRAG_OFF + WFRAG_B;
constexpr size_t WV_B      = 64 * 64 * 4;
constexpr size_t CONV_OFF  = WV_OFF + WV_B;
constexpr size_t CONV_B    = (size_t)Bn * OCn * DHW * 2;           // 56,623,104
constexpr size_t V_OFF     = CONV_OFF + CONV_B;
constexpr size_t V_B       = (size_t)Bn * Gn * DHW * GCn * 2;      // 16,777,216 (bf16)
constexpr size_t SAMP_OFF  = V_OFF + V_B;
constexpr size_t SAMP_B    = (size_t)Bn * Gn * DHW * GCn * 2;      // 16,777,216
constexpr size_t STAT_OFF  = SAMP_OFF + SAMP_B;
// t (bf16, 16.7MB) reuses the xpadh region (dead after conv_mfma)
}

__device__ inline float b2f(short s) {
  union { float f; unsigned u; } x; x.u = ((unsigned)(unsigned short)s) << 16; return x.f;
}
__device__ inline short f2b(float f) {
  __hip_bfloat16 h = __float2bfloat16(f);
  union { __hip_bfloat16 h; short s; } x; x.h = h; return x.s;
}
__device__ inline int iclamp(int v, int lo, int hi) { return v < lo ? lo : (v > hi ? hi : v); }

// ---- zero-fill padded input volume ----
__global__ __launch_bounds__(256) void zerofill(uint4* __restrict__ p, int n16) {
  int i = blockIdx.x * 256 + threadIdx.x;
  if (i < n16) p[i] = make_uint4(0, 0, 0, 0);
}

// ---- transpose-pad x [b,c,d,h,w] f32 -> xpadh [b,dz,hy,wx,c] bf16 (interior) ----
__global__ __launch_bounds__(256) void fillpad(const float* __restrict__ x,
                                               __hip_bfloat16* __restrict__ xpadh) {
  int tid = threadIdx.x;
  int w5 = tid & 31, cq = tid >> 5;
  int p = blockIdx.x * 32 + w5;
  int b = blockIdx.y;
  int w = p & 63, h = (p >> 6) & 63, d = p >> 12;
  const float* xb = x + ((size_t)b * 64 + cq * 8) * DHW + p;
  short8 o8;
#pragma unroll
  for (int j = 0; j < 8; ++j) o8[j] = f2b(xb[(size_t)j * DHW]);
  __hip_bfloat16* ob = xpadh + (size_t)b * (PD * PH * PW * 64)
      + ((((size_t)(d + 1) * 66) + (h + 1)) * 66 + (w + 1)) * 64 + cq * 8;
  *(short8*)ob = o8;
}

// ---- fold pre 1x1 into conv weights (MFMA fragment order) and value projection ----
__global__ __launch_bounds__(256) void fold_weights(
    const float* __restrict__ pre_w, const float* __restrict__ in_proj_w,
    const float* __restrict__ off_w, const float* __restrict__ mask_w,
    short8* __restrict__ Wfrag, float* __restrict__ Wv) {
  int i = blockIdx.x * 256 + threadIdx.x;
  if (i < 64 * 64) {
    int o = i >> 6, c = i & 63;
    float s = 0.f;
    for (int cp = 0; cp < 64; ++cp) s += in_proj_w[o * 64 + cp] * pre_w[cp * 64 + c];
    Wv[i] = s;
    return;
  }
  int t = i - 64 * 64;
  if (t >= 54 * 16 * 64) return;
  int l = t & 63; int rest = t >> 6;
  int mt = rest & 15; int ks = rest >> 4;
  int oc = mt * 16 + (l & 15);
  int tap = ks >> 1;
  int c0 = (ks & 1) * 32 + (l >> 4) * 8;
  float vals[8] = {0.f, 0.f, 0.f, 0.f, 0.f, 0.f, 0.f, 0.f};
  if (oc < OCn) {
    const float* cw = (oc < 162) ? (off_w + (size_t)oc * 64 * 27)
                                 : (mask_w + (size_t)(oc - 162) * 64 * 27);
#pragma unroll 1
    for (int cp = 0; cp < 64; ++cp) {
      float wv = cw[cp * 27 + tap];
      const float* pr = pre_w + cp * 64 + c0;
#pragma unroll
      for (int j = 0; j < 8; ++j) vals[j] += wv * pr[j];
    }
  }
  short8 o8;
#pragma unroll
  for (int j = 0; j < 8; ++j) o8[j] = f2b(vals[j]);
  Wfrag[t] = o8;
}

// ---- value projection v = (in_proj_w @ pre_w) @ x + b, bf16 layout [b,g,p,32] ----
__global__ __launch_bounds__(256) void vproj(
    const float* __restrict__ x, const float* __restrict__ Wv,
    const float* __restrict__ vb, __hip_bfloat16* __restrict__ v) {
  int p = blockIdx.x * 256 + threadIdx.x;
  int b = blockIdx.y;
  const float* xb = x + (size_t)b * Cn * DHW;
  float xv[Cn];
#pragma unroll
  for (int c = 0; c < Cn; ++c) xv[c] = xb[c * DHW + p];
#pragma unroll 1
  for (int g = 0; g < Gn; ++g) {
    float vo[GCn];
#pragma unroll
    for (int j = 0; j < GCn; ++j) {
      int o = g * GCn + j;
      float s = vb[o];
#pragma unroll
      for (int c = 0; c < Cn; ++c) s += Wv[o * Cn + c] * xv[c];
      vo[j] = s;
    }
    short8* dst = (short8*)(v + ((size_t)(b * Gn + g) * DHW + p) * GCn);
#pragma unroll
    for (int q = 0; q < 4; ++q) {
      short8 o8;
#pragma unroll
      for (int j = 0; j < 8; ++j) o8[j] = f2b(vo[q * 8 + j]);
      dst[q] = o8;
    }
  }
}

// ---- MFMA implicit-GEMM 3x3x3 conv: M=256(216) oc x N=128 pos, K=1728 ----
// NO LDS, NO barriers: A (weights, 884KB) and B (xpadh, 20MB) stream from L2.
// 8 waves = 4 oc-quarters x 2 h-rows; 1-step software pipeline.
__global__ __launch_bounds__(512) void conv_mfma(
    const char* __restrict__ xpadh, const char* __restrict__ wfrag,
    const float* __restrict__ off_b, const float* __restrict__ mask_b,
    __hip_bfloat16* __restrict__ convout) {
  int tid = threadIdx.x;
  int h0 = blockIdx.x * 2, d = blockIdx.y, b = blockIdx.z;
  int wid = tid >> 6, l = tid & 63;
  int wm = wid & 3, wn = wid >> 2;                 // oc quarter, h row
  int lm = l & 15, lk = l >> 4;

  const char* abase = wfrag + ((size_t)((wm * 4) * 64 + l)) * 16;   // + ks*16384 + mt*1024
  const char* bbase = xpadh + (size_t)b * (PD * PH * PW * 128)
      + (((d * 66) + (h0 + wn + 1) /*pad: d rows handled by dd*/) * 0);  // placeholder, real below
  bbase = xpadh + (size_t)b * (PD * PH * PW * 128)
      + ((((size_t)d * 66) + (h0 + wn)) * 66 + lm) * 128 + lk * 16;

  f32x4 acc[4][4];
#pragma unroll
  for (int mt = 0; mt < 4; ++mt)
#pragma unroll
    for (int nt = 0; nt < 4; ++nt) acc[mt][nt] = (f32x4){0.f, 0.f, 0.f, 0.f};

  short8 A0[4], B0[4], A1[4], B1[4];

#define LOADS(KS, A, B)                                                     \
  {                                                                         \
    int tap_ = (KS) >> 1, chalf_ = (KS) & 1;                                \
    int dd_ = tap_ / 9, rem_ = tap_ - dd_ * 9;                              \
    int dh_ = rem_ / 3, dw_ = rem_ - dh_ * 3;                               \
    const char* ap_ = abase + (KS) * 16384;                                 \
    _Pragma("unroll")                                                       \
    for (int mt = 0; mt < 4; ++mt) A[mt] = *(const short8*)(ap_ + mt * 1024); \
    const char* bp_ = bbase + (((dd_ * 66 + dh_) * 66 + dw_) * 128 + chalf_ * 64); \
    _Pragma("unroll")                                                       \
    for (int nt = 0; nt < 4; ++nt) B[nt] = *(const short8*)(bp_ + nt * 2048); \
  }

#define MFMAS(A, B)                                                         \
  _Pragma("unroll")                                                         \
  for (int mt = 0; mt < 4; ++mt)                                            \
    _Pragma("unroll")                                                       \
    for (int nt = 0; nt < 4; ++nt)                                          \
      acc[mt][nt] = __builtin_amdgcn_mfma_f32_16x16x32_bf16(A[mt], B[nt], acc[mt][nt], 0, 0, 0);

  LOADS(0, A0, B0)
#pragma unroll 1
  for (int ks = 0; ks < 54; ks += 2) {
    LOADS(ks + 1, A1, B1)
    MFMAS(A0, B0)
    if (ks + 2 < 54) LOADS(ks + 2, A0, B0)
    MFMAS(A1, B1)
  }
#undef LOADS
#undef MFMAS

  int pbase = d * 4096 + (h0 + wn) * 64;
#pragma unroll
  for (int mt = 0; mt < 4; ++mt) {
    int oc0 = wm * 64 + mt * 16 + lk * 4;
#pragma unroll
    for (int r = 0; r < 4; ++r) {
      int oc = oc0 + r;
      if (oc < OCn) {
        float bias = (oc < 162) ? off_b[oc] : mask_b[oc - 162];
        size_t orow = ((size_t)b * OCn + oc) * DHW + pbase;
#pragma unroll
        for (int nt = 0; nt < 4; ++nt)
          convout[orow + nt * 16 + lm] = __float2bfloat16(acc[mt][nt][r] + bias);
      }
    }
  }
}

// ---- deformable trilinear sampling + fused mask softmax ----
// 4 threads per (p,g): 8 channels each; exp cached in LDS; unnormalized accumulate.
__global__ __launch_bounds__(256) void dcn_sample(
    const __hip_bfloat16* __restrict__ convout, const __hip_bfloat16* __restrict__ v,
    __hip_bfloat16* __restrict__ sampled) {
  __shared__ short offm[108 * 64];                 // 13,824 B
  __shared__ float elds[27 * 64];                  // 6,912 B
  int tid = threadIdx.x;
  int bg = blockIdx.y;
  int b = bg >> 1, g = bg & 1;
  int p0 = blockIdx.x * 64;

  const __hip_bfloat16* cb = convout + (size_t)b * OCn * DHW;
#pragma unroll 1
  for (int idx = tid; idx < 108 * 8; idx += 256) {
    int row = idx >> 3, col = idx & 7;
    int oc = (row < 81) ? (g * 81 + row) : (162 + g * Kn + (row - 81));
    *(uint4*)(offm + row * 64 + col * 8) = *(const uint4*)(cb + (size_t)oc * DHW + p0 + col * 8);
  }
  __syncthreads();

  int pl = tid >> 2, q = tid & 3;
  int p = p0 + pl;
  int w = p & 63, h = (p >> 6) & 63, d = p >> 12;

  // softmax denominator (no max-shift: logits are small conv outputs); cache exps in LDS
  float msum = 0.f;
#pragma unroll 1
  for (int k = 0; k < Kn; ++k) {
    float e = __expf(b2f(offm[(81 + k) * 64 + pl]));
    msum += e;
    if (q == 0) elds[k * 64 + pl] = e;
  }
  float rs = 1.f / msum;

  f32x2 acc[4];
#pragma unroll
  for (int j = 0; j < 4; ++j) acc[j] = (f32x2){0.f, 0.f};
  const char* vg = (const char*)v + ((size_t)bg * DHW * GCn + q * 8) * 2;

#pragma unroll 1
  for (int k = 0; k < Kn; ++k) {
    float offd = b2f(offm[(3 * k + 0) * 64 + pl]);
    float offh = b2f(offm[(3 * k + 1) * 64 + pl]);
    float offw = b2f(offm[(3 * k + 2) * 64 + pl]);
    float pd = (float)(d + (k / 9) - 1) + offd * 0.5f;
    float ph = (float)(h + ((k / 3) % 3) - 1) + offh;
    float pw = (float)(w + (k % 3) - 1) + offw;
    float fd = floorf(pd), fh = floorf(ph), fw = floorf(pw);
    float td = pd - fd, th = ph - fh, tw = pw - fw;
    int d0 = (int)fd, h0 = (int)fh, w0 = (int)fw;
    float ek = elds[k * 64 + pl];                  // unnormalized mask weight

    float wd0 = ((unsigned)d0 < (unsigned)Dn) ? (1.f - td) * ek : 0.f;
    float wd1 = ((unsigned)(d0 + 1) < (unsigned)Dn) ? td * ek : 0.f;
    float wh0 = ((unsigned)h0 < (unsigned)Hn) ? (1.f - th) : 0.f;
    float wh1 = ((unsigned)(h0 + 1) < (unsigned)Hn) ? th : 0.f;
    float ww0 = ((unsigned)w0 < (unsigned)Wn) ? (1.f - tw) : 0.f;
    float ww1 = ((unsigned)(w0 + 1) < (unsigned)Wn) ? tw : 0.f;
    // byte offsets, pre-shifted
    int dr0 = iclamp(d0, 0, Dn - 1) << 18, dr1 = iclamp(d0 + 1, 0, Dn - 1) << 18;
    int hr0 = iclamp(h0, 0, Hn - 1) << 12, hr1 = iclamp(h0 + 1, 0, Hn - 1) << 12;
    int wc0 = iclamp(w0, 0, Wn - 1) << 6,  wc1 = iclamp(w0 + 1, 0, Wn - 1) << 6;
    float wdh00 = wd0 * wh0, wdh01 = wd0 * wh1, wdh10 = wd1 * wh0, wdh11 = wd1 * wh1;

    // hi half uses dirty-low-bits float (error <= 2^-8 relative, same as bf16 rounding)
#define CORNER(BOFF, WT)                                                \
    {                                                                   \
      float wt_ = (WT);                                                 \
      f32x2 w2_ = {wt_, wt_};                                           \
      uint4 ua_ = *(const uint4*)(vg + (BOFF));                         \
      f32x2 p0_ = {__uint_as_float(ua_.x << 16), __uint_as_float(ua_.x)}; \
      f32x2 p1_ = {__uint_as_float(ua_.y << 16), __uint_as_float(ua_.y)}; \
      f32x2 p2_ = {__uint_as_float(ua_.z << 16), __uint_as_float(ua_.z)}; \
      f32x2 p3_ = {__uint_as_float(ua_.w << 16), __uint_as_float(ua_.w)}; \
      acc[0] = FMA2(p0_, w2_, acc[0]);                                  \
      acc[1] = FMA2(p1_, w2_, acc[1]);                                  \
      acc[2] = FMA2(p2_, w2_, acc[2]);                                  \
      acc[3] = FMA2(p3_, w2_, acc[3]);                                  \
    }
    CORNER(dr0 + hr0 + wc0, wdh00 * ww0)
    CORNER(dr0 + hr0 + wc1, wdh00 * ww1)
    CORNER(dr0 + hr1 + wc0, wdh01 * ww0)
    CORNER(dr0 + hr1 + wc1, wdh01 * ww1)
    CORNER(dr1 + hr0 + wc0, wdh10 * ww0)
    CORNER(dr1 + hr0 + wc1, wdh10 * ww1)
    CORNER(dr1 + hr1 + wc0, wdh11 * ww0)
    CORNER(dr1 + hr1 + wc1, wdh11 * ww1)
#undef CORNER
  }

  // normalize once at the end
  f32x2 rs2 = {rs, rs};
#pragma unroll
  for (int j = 0; j < 4; ++j) acc[j] = acc[j] * rs2;

  const float* af = (const float*)acc;
  short8 o8;
#pragma unroll
  for (int j = 0; j < 8; ++j) o8[j] = f2b(af[j]);
  *(short8*)(sampled + ((size_t)bg * DHW + p) * GCn + q * 8) = o8;
}

// ---- out_proj: t (bf16, in ws) ----
__global__ __launch_bounds__(256) void outproj(
    const __hip_bfloat16* __restrict__ sampled, const float* __restrict__ Wout,
    const float* __restrict__ ob, __hip_bfloat16* __restrict__ t) {
  int p = blockIdx.x * 256 + threadIdx.x;
  int b = blockIdx.y;
  float sv[Cn];
#pragma unroll
  for (int g = 0; g < Gn; ++g) {
    const short8* src = (const short8*)(sampled) + ((size_t)(b * Gn + g) * DHW + p) * 4;
#pragma unroll
    for (int q = 0; q < 4; ++q) {
      short8 s8 = src[q];
#pragma unroll
      for (int j = 0; j < 8; ++j) sv[g * GCn + q * 8 + j] = b2f(s8[j]);
    }
  }
#pragma unroll 1
  for (int o = 0; o < Cn; ++o) {
    float s = ob[o];
#pragma unroll
    for (int c = 0; c < Cn; ++c) s += Wout[o * Cn + c] * sv[c];
    t[((size_t)b * Cn + o) * DHW + p] = __float2bfloat16(s);
  }
}

// ---- per-(b,c) instance-norm stats (bf16 input, vectorized) ----
__global__ __launch_bounds__(256) void stats_k(const __hip_bfloat16* __restrict__ t,
                                               float* __restrict__ stat) {
  int bc = blockIdx.x;
  const short8* tc = (const short8*)(t + (size_t)bc * DHW);
  float s = 0.f, ss = 0.f;
  for (int i = threadIdx.x; i < DHW / 8; i += 256) {
    short8 s8 = tc[i];
#pragma unroll
    for (int j = 0; j < 8; ++j) { float xv = b2f(s8[j]); s += xv; ss += xv * xv; }
  }
#pragma unroll
  for (int o = 32; o > 0; o >>= 1) { s += __shfl_down(s, o); ss += __shfl_down(ss, o); }
  __shared__ float ls[4], lss[4];
  int wid = threadIdx.x >> 6;
  if ((threadIdx.x & 63) == 0) { ls[wid] = s; lss[wid] = ss; }
  __syncthreads();
  if (threadIdx.x == 0) {
    float S = ls[0] + ls[1] + ls[2] + ls[3];
    float SS = lss[0] + lss[1] + lss[2] + lss[3];
    float mu = S / (float)DHW;
    float var = SS / (float)DHW - mu * mu;
    stat[bc * 2 + 0] = mu;
    stat[bc * 2 + 1] = rsqrtf(var + EPS);
  }
}

// ---- norm + gelu + post 1x1 + gated residual ----
__global__ __launch_bounds__(256) void finalk(
    const __hip_bfloat16* __restrict__ t, const float* __restrict__ x,
    const float* __restrict__ stat,
    const float* __restrict__ gamma, const float* __restrict__ beta,
    const float* __restrict__ Wpost, const float* __restrict__ gate, float* out) {
  int p = blockIdx.x * 256 + threadIdx.x;
  int b = blockIdx.y;
  float sg = 1.f / (1.f + __expf(-gate[0]));
  float nv[Cn];
#pragma unroll
  for (int c = 0; c < Cn; ++c) {
    float mu = stat[(b * Cn + c) * 2 + 0];
    float rstd = stat[(b * Cn + c) * 2 + 1];
    float tv = b2f(((const short*)t)[((size_t)b * Cn + c) * DHW + p]);
    float yv = (tv - mu) * rstd * gamma[c] + beta[c];
    float u = 0.7978845608028654f * (yv + 0.044715f * yv * yv * yv);
    float e = __expf(2.f * u);
    float th = 1.f - 2.f / (e + 1.f);
    nv[c] = 0.5f * yv * (1.f + th);
  }
#pragma unroll 1
  for (int o = 0; o < Cn; ++o) {
    float s = 0.f;
#pragma unroll
    for (int c = 0; c < Cn; ++c) s += Wpost[o * Cn + c] * nv[c];
    size_t i = ((size_t)b * Cn + o) * DHW + p;
    out[i] = x[i] + sg * s;
  }
}

extern "C" void kernel_launch(void* const* d_in, const int* in_sizes, int n_in,
                              void* d_out, int out_size, void* d_ws, size_t ws_size,
                              hipStream_t stream) {
  const float* x          = (const float*)d_in[0];
  const float* gate       = (const float*)d_in[1];
  const float* pre_w      = (const float*)d_in[2];
  const float* post_w     = (const float*)d_in[3];
  const float* in_proj_w  = (const float*)d_in[4];
  const float* in_proj_b  = (const float*)d_in[5];
  const float* out_proj_w = (const float*)d_in[6];
  const float* out_proj_b = (const float*)d_in[7];
  const float* off_w      = (const float*)d_in[8];
  const float* off_b      = (const float*)d_in[9];
  const float* mask_w     = (const float*)d_in[10];
  const float* mask_b     = (const float*)d_in[11];
  const float* in_gamma   = (const float*)d_in[12];
  const float* in_beta    = (const float*)d_in[13];

  char* ws = (char*)d_ws;
  __hip_bfloat16* xpadh = (__hip_bfloat16*)(ws + XPADH_OFF);
  short8* Wfrag  = (short8*)(ws + WFRAG_OFF);
  float* Wv      = (float*)(ws + WV_OFF);
  __hip_bfloat16* convout = (__hip_bfloat16*)(ws + CONV_OFF);
  __hip_bfloat16* v       = (__hip_bfloat16*)(ws + V_OFF);
  __hip_bfloat16* sampled = (__hip_bfloat16*)(ws + SAMP_OFF);
  float* stat    = (float*)(ws + STAT_OFF);
  __hip_bfloat16* t = (__hip_bfloat16*)(ws + XPADH_OFF);   // reuses xpadh region
  float* out = (float*)d_out;

  int zf16 = (int)(XPADH_B / 16);
  zerofill<<<(zf16 + 255) / 256, 256, 0, stream>>>((uint4*)xpadh, zf16);
  fillpad<<<dim3(DHW / 32, Bn), 256, 0, stream>>>(x, xpadh);
  int foldN = (64 * 64 + 54 * 16 * 64 + 255) / 256;
  fold_weights<<<foldN, 256, 0, stream>>>(pre_w, in_proj_w, off_w, mask_w, Wfrag, Wv);
  vproj<<<dim3(DHW / 256, Bn), 256, 0, stream>>>(x, Wv, in_proj_b, v);
  conv_mfma<<<dim3(32, 16, 2), 512, 0, stream>>>((const char*)xpadh, (const char*)Wfrag,
                                                 off_b, mask_b, convout);
  dcn_sample<<<dim3(DHW / 64, Bn * Gn), 256, 0, stream>>>(convout, v, sampled);
  outproj<<<dim3(DHW / 256, Bn), 256, 0, stream>>>(sampled, out_proj_w, out_proj_b, t);
  stats_k<<<Bn * Cn, 256, 0, stream>>>(t, stat);
  finalk<<<dim3(DHW / 256, Bn), 256, 0, stream>>>(t, x, stat, in_gamma, in_beta,
                                                  post_w, gate, out);
}

// Round 8
// 462.661 us; speedup vs baseline: 1.3095x; 1.3095x over previous
//
#include <hip/hip_runtime.h>
#include <hip/hip_bf16.h>

typedef short short8 __attribute__((ext_vector_type(8)));
typedef float f32x4 __attribute__((ext_vector_type(4)));
typedef float f32x2 __attribute__((ext_vector_type(2)));

#if __has_builtin(__builtin_elementwise_fma)
#define FMA2(a, b, c) __builtin_elementwise_fma((a), (b), (c))
#else
#define FMA2(a, b, c) ((a) * (b) + (c))
#endif

namespace {
constexpr int Bn = 2, Cn = 64, Dn = 16, Hn = 64, Wn = 64;
constexpr int Gn = 2, Kn = 27, GCn = 32;
constexpr int DHW = Dn * Hn * Wn;                 // 65536
constexpr int OCn = 216;                          // 162 off + 54 mask
constexpr int PD = 18, PH = 66, PW = 66;
constexpr float EPS = 1e-5f;

// conv patch: 3d x 4h x 66w rows of 128B (64ch bf16)
constexpr int PROWS = 12 * 66;                    // 792
constexpr int PATCH_B = PROWS * 128;              // 101376

constexpr size_t XPADH_OFF = 0;
constexpr size_t XPADH_B   = (size_t)Bn * PD * PH * PW * Cn * 2;   // 20,072,448
constexpr size_t WFRAG_OFF = XPADH_OFF + XPADH_B;
constexpr size_t WFRAG_B   = (size_t)54 * 16 * 64 * 16;            // 884,736
constexpr size_t WV_OFF    = WFRAG_OFF + WFRAG_B;
constexpr size_t WV_B      = 64 * 64 * 4;
constexpr size_t CONV_OFF  = WV_OFF + WV_B;
constexpr size_t CONV_B    = (size_t)Bn * OCn * DHW * 2;           // 56,623,104
constexpr size_t V_OFF     = CONV_OFF + CONV_B;
constexpr size_t V_B       = (size_t)Bn * Gn * DHW * GCn * 2;      // 16,777,216 (bf16)
constexpr size_t SAMP_OFF  = V_OFF + V_B;
constexpr size_t SAMP_B    = (size_t)Bn * Gn * DHW * GCn * 2;      // 16,777,216
constexpr size_t STAT_OFF  = SAMP_OFF + SAMP_B;
// t (bf16, 16.7MB) reuses the xpadh region (dead after conv_mfma)
}

__device__ inline float b2f(short s) {
  union { float f; unsigned u; } x; x.u = ((unsigned)(unsigned short)s) << 16; return x.f;
}
__device__ inline short f2b(float f) {
  __hip_bfloat16 h = __float2bfloat16(f);
  union { __hip_bfloat16 h; short s; } x; x.h = h; return x.s;
}
__device__ inline int iclamp(int v, int lo, int hi) { return v < lo ? lo : (v > hi ? hi : v); }

// ---- zero-fill padded input volume ----
__global__ __launch_bounds__(256) void zerofill(uint4* __restrict__ p, int n16) {
  int i = blockIdx.x * 256 + threadIdx.x;
  if (i < n16) p[i] = make_uint4(0, 0, 0, 0);
}

// ---- transpose-pad x [b,c,d,h,w] f32 -> xpadh [b,dz,hy,wx,c] bf16 (interior) ----
__global__ __launch_bounds__(256) void fillpad(const float* __restrict__ x,
                                               __hip_bfloat16* __restrict__ xpadh) {
  int tid = threadIdx.x;
  int w5 = tid & 31, cq = tid >> 5;
  int p = blockIdx.x * 32 + w5;
  int b = blockIdx.y;
  int w = p & 63, h = (p >> 6) & 63, d = p >> 12;
  const float* xb = x + ((size_t)b * 64 + cq * 8) * DHW + p;
  short8 o8;
#pragma unroll
  for (int j = 0; j < 8; ++j) o8[j] = f2b(xb[(size_t)j * DHW]);
  __hip_bfloat16* ob = xpadh + (size_t)b * (PD * PH * PW * 64)
      + ((((size_t)(d + 1) * 66) + (h + 1)) * 66 + (w + 1)) * 64 + cq * 8;
  *(short8*)ob = o8;
}

// ---- fold pre 1x1 into conv weights (MFMA fragment order) and value projection ----
__global__ __launch_bounds__(256) void fold_weights(
    const float* __restrict__ pre_w, const float* __restrict__ in_proj_w,
    const float* __restrict__ off_w, const float* __restrict__ mask_w,
    short8* __restrict__ Wfrag, float* __restrict__ Wv) {
  int i = blockIdx.x * 256 + threadIdx.x;
  if (i < 64 * 64) {
    int o = i >> 6, c = i & 63;
    float s = 0.f;
    for (int cp = 0; cp < 64; ++cp) s += in_proj_w[o * 64 + cp] * pre_w[cp * 64 + c];
    Wv[i] = s;
    return;
  }
  int t = i - 64 * 64;
  if (t >= 54 * 16 * 64) return;
  int l = t & 63; int rest = t >> 6;
  int mt = rest & 15; int ks = rest >> 4;
  int oc = mt * 16 + (l & 15);
  int tap = ks >> 1;
  int c0 = (ks & 1) * 32 + (l >> 4) * 8;
  float vals[8] = {0.f, 0.f, 0.f, 0.f, 0.f, 0.f, 0.f, 0.f};
  if (oc < OCn) {
    const float* cw = (oc < 162) ? (off_w + (size_t)oc * 64 * 27)
                                 : (mask_w + (size_t)(oc - 162) * 64 * 27);
#pragma unroll 1
    for (int cp = 0; cp < 64; ++cp) {
      float wv = cw[cp * 27 + tap];
      const float* pr = pre_w + cp * 64 + c0;
#pragma unroll
      for (int j = 0; j < 8; ++j) vals[j] += wv * pr[j];
    }
  }
  short8 o8;
#pragma unroll
  for (int j = 0; j < 8; ++j) o8[j] = f2b(vals[j]);
  Wfrag[t] = o8;
}

// ---- value projection v = (in_proj_w @ pre_w) @ x + b, bf16 layout [b,g,p,32] ----
__global__ __launch_bounds__(256) void vproj(
    const float* __restrict__ x, const float* __restrict__ Wv,
    const float* __restrict__ vb, __hip_bfloat16* __restrict__ v) {
  int p = blockIdx.x * 256 + threadIdx.x;
  int b = blockIdx.y;
  const float* xb = x + (size_t)b * Cn * DHW;
  float xv[Cn];
#pragma unroll
  for (int c = 0; c < Cn; ++c) xv[c] = xb[c * DHW + p];
#pragma unroll 1
  for (int g = 0; g < Gn; ++g) {
    float vo[GCn];
#pragma unroll
    for (int j = 0; j < GCn; ++j) {
      int o = g * GCn + j;
      float s = vb[o];
#pragma unroll
      for (int c = 0; c < Cn; ++c) s += Wv[o * Cn + c] * xv[c];
      vo[j] = s;
    }
    short8* dst = (short8*)(v + ((size_t)(b * Gn + g) * DHW + p) * GCn);
#pragma unroll
    for (int q = 0; q < 4; ++q) {
      short8 o8;
#pragma unroll
      for (int j = 0; j < 8; ++j) o8[j] = f2b(vo[q * 8 + j]);
      dst[q] = o8;
    }
  }
}

// ---- MFMA implicit-GEMM 3x3x3 conv: M=256(216) oc x N=128 pos, K=1728 ----
// Hybrid: B from static LDS patch (ONE barrier total); A streamed global->VGPR
// (coalesced, L2-resident 884KB table) with 2-step pipeline. No per-step barrier.
__global__ __launch_bounds__(512) void conv_mfma(
    const char* __restrict__ xpadh, const char* __restrict__ wfrag,
    const float* __restrict__ off_b, const float* __restrict__ mask_b,
    __hip_bfloat16* __restrict__ convout) {
  __shared__ char lds[PATCH_B];                    // 101,376 B
  int tid = threadIdx.x;
  int h0 = blockIdx.x * 2, d = blockIdx.y, b = blockIdx.z;

  // stage patch (all 27 taps' B-data), XOR-swizzled rows
  const char* xb = xpadh + (size_t)b * (PD * PH * PW * 128);
  for (int idx = tid; idx < PROWS * 8; idx += 512) {
    int s = idx >> 3, slot = idx & 7;
    int r12 = s / 66, wx = s - r12 * 66;
    int dp = r12 >> 2, hp = r12 & 3;
    const char* g = xb + ((((size_t)(d + dp)) * 66 + (h0 + hp)) * 66 + wx) * 128 + slot * 16;
    *(uint4*)(lds + s * 128 + ((slot ^ (s & 7)) << 4)) = *(const uint4*)g;
  }
  __syncthreads();

  int wid = tid >> 6, l = tid & 63;
  int wm = wid & 3, wn = wid >> 2;                 // oc quarter, h row
  int lm = l & 15, lk = l >> 4;
  const char* abase = wfrag + ((size_t)((wm * 4) * 64 + l)) * 16;  // + ks*16384 + mt*1024

  f32x4 acc[4][4];
#pragma unroll
  for (int mt = 0; mt < 4; ++mt)
#pragma unroll
    for (int nt = 0; nt < 4; ++nt) acc[mt][nt] = (f32x4){0.f, 0.f, 0.f, 0.f};

  short8 A0[4], B0[4], A1[4], B1[4];

#define LOADA(KS, A)                                                          \
  {                                                                           \
    const char* ap_ = abase + (KS) * 16384;                                   \
    _Pragma("unroll")                                                         \
    for (int mt = 0; mt < 4; ++mt) A[mt] = *(const short8*)(ap_ + mt * 1024); \
  }
#define LOADB(KS, B)                                                          \
  {                                                                           \
    int tap_ = (KS) >> 1;                                                     \
    int dd_ = tap_ / 9, rem_ = tap_ - dd_ * 9;                                \
    int dh_ = rem_ / 3, dw_ = rem_ - dh_ * 3;                                 \
    int srow_ = (dd_ * 4 + wn + dh_) * 66 + dw_;                              \
    int uslot_ = 4 * ((KS) & 1) + lk;                                         \
    _Pragma("unroll")                                                         \
    for (int nt = 0; nt < 4; ++nt) {                                          \
      int sr_ = srow_ + nt * 16 + lm;                                         \
      B[nt] = *(const short8*)(lds + sr_ * 128 + ((uslot_ ^ (sr_ & 7)) << 4)); \
    }                                                                         \
  }
#define MFMAS(A, B)                                                           \
  __builtin_amdgcn_s_setprio(1);                                              \
  _Pragma("unroll")                                                           \
  for (int mt = 0; mt < 4; ++mt)                                              \
    _Pragma("unroll")                                                         \
    for (int nt = 0; nt < 4; ++nt)                                            \
      acc[mt][nt] = __builtin_amdgcn_mfma_f32_16x16x32_bf16(A[mt], B[nt], acc[mt][nt], 0, 0, 0); \
  __builtin_amdgcn_s_setprio(0);

  LOADA(0, A0) LOADB(0, B0)
#pragma unroll 1
  for (int ks = 0; ks < 54; ks += 2) {
    LOADA(ks + 1, A1) LOADB(ks + 1, B1)
    MFMAS(A0, B0)
    if (ks + 2 < 54) { LOADA(ks + 2, A0) LOADB(ks + 2, B0) }
    MFMAS(A1, B1)
  }
#undef LOADA
#undef LOADB
#undef MFMAS

  int pbase = d * 4096 + (h0 + wn) * 64;
#pragma unroll
  for (int mt = 0; mt < 4; ++mt) {
    int oc0 = wm * 64 + mt * 16 + lk * 4;
#pragma unroll
    for (int r = 0; r < 4; ++r) {
      int oc = oc0 + r;
      if (oc < OCn) {
        float bias = (oc < 162) ? off_b[oc] : mask_b[oc - 162];
        size_t orow = ((size_t)b * OCn + oc) * DHW + pbase;
#pragma unroll
        for (int nt = 0; nt < 4; ++nt)
          convout[orow + nt * 16 + lm] = __float2bfloat16(acc[mt][nt][r] + bias);
      }
    }
  }
}

// ---- deformable trilinear sampling + fused mask softmax ----
// 4 threads per (p,g): 8 channels each; exp cached in LDS; unnormalized accumulate.
__global__ __launch_bounds__(256) void dcn_sample(
    const __hip_bfloat16* __restrict__ convout, const __hip_bfloat16* __restrict__ v,
    __hip_bfloat16* __restrict__ sampled) {
  __shared__ short offm[108 * 64];                 // 13,824 B
  __shared__ float elds[27 * 64];                  // 6,912 B
  int tid = threadIdx.x;
  int bg = blockIdx.y;
  int b = bg >> 1, g = bg & 1;
  int p0 = blockIdx.x * 64;

  const __hip_bfloat16* cb = convout + (size_t)b * OCn * DHW;
#pragma unroll 1
  for (int idx = tid; idx < 108 * 8; idx += 256) {
    int row = idx >> 3, col = idx & 7;
    int oc = (row < 81) ? (g * 81 + row) : (162 + g * Kn + (row - 81));
    *(uint4*)(offm + row * 64 + col * 8) = *(const uint4*)(cb + (size_t)oc * DHW + p0 + col * 8);
  }
  __syncthreads();

  int pl = tid >> 2, q = tid & 3;
  int p = p0 + pl;
  int w = p & 63, h = (p >> 6) & 63, d = p >> 12;

  // softmax denominator (no max-shift: logits are small conv outputs); cache exps in LDS
  float msum = 0.f;
#pragma unroll 1
  for (int k = 0; k < Kn; ++k) {
    float e = __expf(b2f(offm[(81 + k) * 64 + pl]));
    msum += e;
    if (q == 0) elds[k * 64 + pl] = e;
  }
  float rs = 1.f / msum;

  f32x2 acc[4];
#pragma unroll
  for (int j = 0; j < 4; ++j) acc[j] = (f32x2){0.f, 0.f};
  const char* vg = (const char*)v + ((size_t)bg * DHW * GCn + q * 8) * 2;

#pragma unroll 1
  for (int k = 0; k < Kn; ++k) {
    float offd = b2f(offm[(3 * k + 0) * 64 + pl]);
    float offh = b2f(offm[(3 * k + 1) * 64 + pl]);
    float offw = b2f(offm[(3 * k + 2) * 64 + pl]);
    float pd = (float)(d + (k / 9) - 1) + offd * 0.5f;
    float ph = (float)(h + ((k / 3) % 3) - 1) + offh;
    float pw = (float)(w + (k % 3) - 1) + offw;
    float fd = floorf(pd), fh = floorf(ph), fw = floorf(pw);
    float td = pd - fd, th = ph - fh, tw = pw - fw;
    int d0 = (int)fd, h0 = (int)fh, w0 = (int)fw;
    float ek = elds[k * 64 + pl];                  // unnormalized mask weight

    float wd0 = ((unsigned)d0 < (unsigned)Dn) ? (1.f - td) * ek : 0.f;
    float wd1 = ((unsigned)(d0 + 1) < (unsigned)Dn) ? td * ek : 0.f;
    float wh0 = ((unsigned)h0 < (unsigned)Hn) ? (1.f - th) : 0.f;
    float wh1 = ((unsigned)(h0 + 1) < (unsigned)Hn) ? th : 0.f;
    float ww0 = ((unsigned)w0 < (unsigned)Wn) ? (1.f - tw) : 0.f;
    float ww1 = ((unsigned)(w0 + 1) < (unsigned)Wn) ? tw : 0.f;
    int dr0 = iclamp(d0, 0, Dn - 1) << 18, dr1 = iclamp(d0 + 1, 0, Dn - 1) << 18;
    int hr0 = iclamp(h0, 0, Hn - 1) << 12, hr1 = iclamp(h0 + 1, 0, Hn - 1) << 12;
    int wc0 = iclamp(w0, 0, Wn - 1) << 6,  wc1 = iclamp(w0 + 1, 0, Wn - 1) << 6;
    float wdh00 = wd0 * wh0, wdh01 = wd0 * wh1, wdh10 = wd1 * wh0, wdh11 = wd1 * wh1;

#define CORNER(BOFF, WT)                                                \
    {                                                                   \
      float wt_ = (WT);                                                 \
      f32x2 w2_ = {wt_, wt_};                                           \
      uint4 ua_ = *(const uint4*)(vg + (BOFF));                         \
      f32x2 p0_ = {__uint_as_float(ua_.x << 16), __uint_as_float(ua_.x)}; \
      f32x2 p1_ = {__uint_as_float(ua_.y << 16), __uint_as_float(ua_.y)}; \
      f32x2 p2_ = {__uint_as_float(ua_.z << 16), __uint_as_float(ua_.z)}; \
      f32x2 p3_ = {__uint_as_float(ua_.w << 16), __uint_as_float(ua_.w)}; \
      acc[0] = FMA2(p0_, w2_, acc[0]);                                  \
      acc[1] = FMA2(p1_, w2_, acc[1]);                                  \
      acc[2] = FMA2(p2_, w2_, acc[2]);                                  \
      acc[3] = FMA2(p3_, w2_, acc[3]);                                  \
    }
    CORNER(dr0 + hr0 + wc0, wdh00 * ww0)
    CORNER(dr0 + hr0 + wc1, wdh00 * ww1)
    CORNER(dr0 + hr1 + wc0, wdh01 * ww0)
    CORNER(dr0 + hr1 + wc1, wdh01 * ww1)
    CORNER(dr1 + hr0 + wc0, wdh10 * ww0)
    CORNER(dr1 + hr0 + wc1, wdh10 * ww1)
    CORNER(dr1 + hr1 + wc0, wdh11 * ww0)
    CORNER(dr1 + hr1 + wc1, wdh11 * ww1)
#undef CORNER
  }

  f32x2 rs2 = {rs, rs};
#pragma unroll
  for (int j = 0; j < 4; ++j) acc[j] = acc[j] * rs2;

  const float* af = (const float*)acc;
  short8 o8;
#pragma unroll
  for (int j = 0; j < 8; ++j) o8[j] = f2b(af[j]);
  *(short8*)(sampled + ((size_t)bg * DHW + p) * GCn + q * 8) = o8;
}

// ---- out_proj: t (bf16, in ws) ----
__global__ __launch_bounds__(256) void outproj(
    const __hip_bfloat16* __restrict__ sampled, const float* __restrict__ Wout,
    const float* __restrict__ ob, __hip_bfloat16* __restrict__ t) {
  int p = blockIdx.x * 256 + threadIdx.x;
  int b = blockIdx.y;
  float sv[Cn];
#pragma unroll
  for (int g = 0; g < Gn; ++g) {
    const short8* src = (const short8*)(sampled) + ((size_t)(b * Gn + g) * DHW + p) * 4;
#pragma unroll
    for (int q = 0; q < 4; ++q) {
      short8 s8 = src[q];
#pragma unroll
      for (int j = 0; j < 8; ++j) sv[g * GCn + q * 8 + j] = b2f(s8[j]);
    }
  }
#pragma unroll 1
  for (int o = 0; o < Cn; ++o) {
    float s = ob[o];
#pragma unroll
    for (int c = 0; c < Cn; ++c) s += Wout[o * Cn + c] * sv[c];
    t[((size_t)b * Cn + o) * DHW + p] = __float2bfloat16(s);
  }
}

// ---- per-(b,c) instance-norm stats (bf16 input, vectorized) ----
__global__ __launch_bounds__(256) void stats_k(const __hip_bfloat16* __restrict__ t,
                                               float* __restrict__ stat) {
  int bc = blockIdx.x;
  const short8* tc = (const short8*)(t + (size_t)bc * DHW);
  float s = 0.f, ss = 0.f;
  for (int i = threadIdx.x; i < DHW / 8; i += 256) {
    short8 s8 = tc[i];
#pragma unroll
    for (int j = 0; j < 8; ++j) { float xv = b2f(s8[j]); s += xv; ss += xv * xv; }
  }
#pragma unroll
  for (int o = 32; o > 0; o >>= 1) { s += __shfl_down(s, o); ss += __shfl_down(ss, o); }
  __shared__ float ls[4], lss[4];
  int wid = threadIdx.x >> 6;
  if ((threadIdx.x & 63) == 0) { ls[wid] = s; lss[wid] = ss; }
  __syncthreads();
  if (threadIdx.x == 0) {
    float S = ls[0] + ls[1] + ls[2] + ls[3];
    float SS = lss[0] + lss[1] + lss[2] + lss[3];
    float mu = S / (float)DHW;
    float var = SS / (float)DHW - mu * mu;
    stat[bc * 2 + 0] = mu;
    stat[bc * 2 + 1] = rsqrtf(var + EPS);
  }
}

// ---- norm + gelu + post 1x1 + gated residual ----
__global__ __launch_bounds__(256) void finalk(
    const __hip_bfloat16* __restrict__ t, const float* __restrict__ x,
    const float* __restrict__ stat,
    const float* __restrict__ gamma, const float* __restrict__ beta,
    const float* __restrict__ Wpost, const float* __restrict__ gate, float* out) {
  int p = blockIdx.x * 256 + threadIdx.x;
  int b = blockIdx.y;
  float sg = 1.f / (1.f + __expf(-gate[0]));
  float nv[Cn];
#pragma unroll
  for (int c = 0; c < Cn; ++c) {
    float mu = stat[(b * Cn + c) * 2 + 0];
    float rstd = stat[(b * Cn + c) * 2 + 1];
    float tv = b2f(((const short*)t)[((size_t)b * Cn + c) * DHW + p]);
    float yv = (tv - mu) * rstd * gamma[c] + beta[c];
    float u = 0.7978845608028654f * (yv + 0.044715f * yv * yv * yv);
    float e = __expf(2.f * u);
    float th = 1.f - 2.f / (e + 1.f);
    nv[c] = 0.5f * yv * (1.f + th);
  }
#pragma unroll 1
  for (int o = 0; o < Cn; ++o) {
    float s = 0.f;
#pragma unroll
    for (int c = 0; c < Cn; ++c) s += Wpost[o * Cn + c] * nv[c];
    size_t i = ((size_t)b * Cn + o) * DHW + p;
    out[i] = x[i] + sg * s;
  }
}

extern "C" void kernel_launch(void* const* d_in, const int* in_sizes, int n_in,
                              void* d_out, int out_size, void* d_ws, size_t ws_size,
                              hipStream_t stream) {
  const float* x          = (const float*)d_in[0];
  const float* gate       = (const float*)d_in[1];
  const float* pre_w      = (const float*)d_in[2];
  const float* post_w     = (const float*)d_in[3];
  const float* in_proj_w  = (const float*)d_in[4];
  const float* in_proj_b  = (const float*)d_in[5];
  const float* out_proj_w = (const float*)d_in[6];
  const float* out_proj_b = (const float*)d_in[7];
  const float* off_w      = (const float*)d_in[8];
  const float* off_b      = (const float*)d_in[9];
  const float* mask_w     = (const float*)d_in[10];
  const float* mask_b     = (const float*)d_in[11];
  const float* in_gamma   = (const float*)d_in[12];
  const float* in_beta    = (const float*)d_in[13];

  char* ws = (char*)d_ws;
  __hip_bfloat16* xpadh = (__hip_bfloat16*)(ws + XPADH_OFF);
  short8* Wfrag  = (short8*)(ws + WFRAG_OFF);
  float* Wv      = (float*)(ws + WV_OFF);
  __hip_bfloat16* convout = (__hip_bfloat16*)(ws + CONV_OFF);
  __hip_bfloat16* v       = (__hip_bfloat16*)(ws + V_OFF);
  __hip_bfloat16* sampled = (__hip_bfloat16*)(ws + SAMP_OFF);
  float* stat    = (float*)(ws + STAT_OFF);
  __hip_bfloat16* t = (__hip_bfloat16*)(ws + XPADH_OFF);   // reuses xpadh region
  float* out = (float*)d_out;

  int zf16 = (int)(XPADH_B / 16);
  zerofill<<<(zf16 + 255) / 256, 256, 0, stream>>>((uint4*)xpadh, zf16);
  fillpad<<<dim3(DHW / 32, Bn), 256, 0, stream>>>(x, xpadh);
  int foldN = (64 * 64 + 54 * 16 * 64 + 255) / 256;
  fold_weights<<<foldN, 256, 0, stream>>>(pre_w, in_proj_w, off_w, mask_w, Wfrag, Wv);
  vproj<<<dim3(DHW / 256, Bn), 256, 0, stream>>>(x, Wv, in_proj_b, v);
  conv_mfma<<<dim3(32, 16, 2), 512, 0, stream>>>((const char*)xpadh, (const char*)Wfrag,
                                                 off_b, mask_b, convout);
  dcn_sample<<<dim3(DHW / 64, Bn * Gn), 256, 0, stream>>>(convout, v, sampled);
  outproj<<<dim3(DHW / 256, Bn), 256, 0, stream>>>(sampled, out_proj_w, out_proj_b, t);
  stats_k<<<Bn * Cn, 256, 0, stream>>>(t, stat);
  finalk<<<dim3(DHW / 256, Bn), 256, 0, stream>>>(t, x, stat, in_gamma, in_beta,
                                                  post_w, gate, out);
}